// Round 4
// baseline (143.591 us; speedup 1.0000x reference)
//
#include <hip/hip_runtime.h>

// Chamfer distance loss over equal-size clusters (C=128, P=1024, DIM=3).
// Reference excludes the highest cluster id -> clusters 0..126 contribute.
//
// R4: one block per (cluster, direction) = 254 blocks x 1024 threads.
// Thread (qi = tid&63, seg = tid>>6) owns Q=16 queries {k*64+qi} and sweeps
// targets [seg*64, seg*64+64).
//  - LDS plane (SoA) layout: sx/sy/sz/sh[1024]; one ds_read_b128 per plane
//    yields 4 consecutive targets' components -> 1024 wave-b128/block
//    (half of R3), wave-uniform addresses (broadcast, conflict-free).
//  - Packed fp32: expanded form d = (h_j - 2 a.b_j) + |a|^2 computed two
//    targets at a time with v_pk_fma_f32 (<2 x float> elementwise fma);
//    per 4 pairs per query: 6 pk_fma + 2 v_min3 = 2.0 VALU/pair.
//  - Combine across segs via LDS atomicMin on bit-cast uints (distances are
//    >= 0 up to rounding; uint order == float order; a ~1e-7 negative
//    rounding tie is irrelevant vs the 4.4e2 threshold). colmin addresses
//    are distinct within a wave -> no same-address serialization.

#define PTS  1024
#define ACTIVE_CLUSTERS 127
#define QG   64            // queries per k-slice (= threads per segment)
#define Q    16            // queries per thread   (Q*QG == PTS)
#define SEG  16            // target segments      (SEG*QG == TPB)
#define TPB  1024
#define TSEG (PTS / SEG)   // 64 targets per segment

typedef float v2f __attribute__((ext_vector_type(2)));

static __device__ __forceinline__ v2f splat2(float a) {
    v2f r; r.x = a; r.y = a; return r;
}

__global__ __launch_bounds__(TPB) void chamfer_kernel(
    const float* __restrict__ pts_in,
    const float* __restrict__ pts_out,
    float* __restrict__ out)
{
    const int c   = blockIdx.x >> 1;
    const int dir = blockIdx.x & 1;

    const float* __restrict__ query  = dir ? pts_out : pts_in;
    const float* __restrict__ target = dir ? pts_in  : pts_out;

    __shared__ __align__(16) float sx[PTS];
    __shared__ __align__(16) float sy[PTS];
    __shared__ __align__(16) float sz[PTS];
    __shared__ __align__(16) float sh[PTS];
    __shared__ unsigned colmin[PTS];
    __shared__ float wsum[16];

    const int tid = threadIdx.x;
    const int qi  = tid & (QG - 1);
    const int seg = tid >> 6;
    const size_t base = (size_t)c * PTS * 3;

    colmin[tid] = 0x7f7fffffu;  // FLT_MAX bits

    // Stage targets into plane (SoA) LDS layout.
    {
        const float* tp = target + base + (size_t)tid * 3;
        float x = tp[0], y = tp[1], z = tp[2];
        sx[tid] = x; sy[tid] = y; sz[tid] = z;
        sh[tid] = fmaf(x, x, fmaf(y, y, z * z));
    }

    // Load Q query points (as -2*coords and |a|^2).
    float qx[Q], qy[Q], qz[Q], qn[Q], mn[Q];
    #pragma unroll
    for (int k = 0; k < Q; ++k) {
        const float* qp = query + base + (size_t)(k * QG + qi) * 3;
        float ax = qp[0], ay = qp[1], az = qp[2];
        qn[k] = fmaf(ax, ax, fmaf(ay, ay, az * az));
        qx[k] = -2.0f * ax;
        qy[k] = -2.0f * ay;
        qz[k] = -2.0f * az;
        mn[k] = 3.4e38f;
    }
    __syncthreads();

    // Sweep this segment's 64 targets, 4 at a time (b128 per plane).
    const int j0 = seg * TSEG;
    #pragma unroll 2
    for (int jj = 0; jj < TSEG; jj += 4) {
        const float4 bx = *(const float4*)&sx[j0 + jj];
        const float4 by = *(const float4*)&sy[j0 + jj];
        const float4 bz = *(const float4*)&sz[j0 + jj];
        const float4 bh = *(const float4*)&sh[j0 + jj];
        v2f bx01; bx01.x = bx.x; bx01.y = bx.y;
        v2f bx23; bx23.x = bx.z; bx23.y = bx.w;
        v2f by01; by01.x = by.x; by01.y = by.y;
        v2f by23; by23.x = by.z; by23.y = by.w;
        v2f bz01; bz01.x = bz.x; bz01.y = bz.y;
        v2f bz23; bz23.x = bz.z; bz23.y = bz.w;
        v2f bh01; bh01.x = bh.x; bh01.y = bh.y;
        v2f bh23; bh23.x = bh.z; bh23.y = bh.w;
        #pragma unroll
        for (int k = 0; k < Q; ++k) {
            v2f s01 = __builtin_elementwise_fma(splat2(qx[k]), bx01, bh01);
            s01 = __builtin_elementwise_fma(splat2(qy[k]), by01, s01);
            s01 = __builtin_elementwise_fma(splat2(qz[k]), bz01, s01);
            v2f s23 = __builtin_elementwise_fma(splat2(qx[k]), bx23, bh23);
            s23 = __builtin_elementwise_fma(splat2(qy[k]), by23, s23);
            s23 = __builtin_elementwise_fma(splat2(qz[k]), bz23, s23);
            mn[k] = fminf(fminf(s01.x, s01.y), mn[k]);   // v_min3_f32
            mn[k] = fminf(fminf(s23.x, s23.y), mn[k]);   // v_min3_f32
        }
    }

    // Cross-seg combine: LDS atomicMin on uint bit patterns (d >= 0).
    #pragma unroll
    for (int k = 0; k < Q; ++k) {
        float v = mn[k] + qn[k];
        atomicMin(&colmin[k * QG + qi], __float_as_uint(v));
    }
    __syncthreads();

    // Sum the 1024 per-query mins: wave shuffle, cross-wave, one atomicAdd.
    float v = __uint_as_float(colmin[tid]);
    #pragma unroll
    for (int off = 32; off > 0; off >>= 1)
        v += __shfl_down(v, off, 64);

    const int wave = tid >> 6;
    const int lane = tid & 63;
    if (lane == 0) wsum[wave] = v;
    __syncthreads();

    if (wave == 0) {
        float t = (lane < 16) ? wsum[lane] : 0.0f;
        #pragma unroll
        for (int off = 8; off > 0; off >>= 1)
            t += __shfl_down(t, off, 64);
        if (lane == 0) atomicAdd(out, t);
    }
}

extern "C" void kernel_launch(void* const* d_in, const int* in_sizes, int n_in,
                              void* d_out, int out_size, void* d_ws, size_t ws_size,
                              hipStream_t stream) {
    const float* input_points  = (const float*)d_in[0];
    const float* output_points = (const float*)d_in[2];
    float* out = (float*)d_out;

    hipMemsetAsync(out, 0, sizeof(float), stream);

    chamfer_kernel<<<dim3(ACTIVE_CLUSTERS * 2), dim3(TPB), 0, stream>>>(
        input_points, output_points, out);
}